// Round 5
// baseline (105.168 us; speedup 1.0000x reference)
//
#include <hip/hip_runtime.h>
#include <stdint.h>

// Problem constants (N=2, S=2048, E=1024, H=16, D=64)
#define S_LEN 2048
#define EMB 1024
#define NHEADS 16
#define HD 64
#define LOG2E 1.4426950408889634f

typedef __bf16 bf16x8 __attribute__((ext_vector_type(8)));
typedef float f32x4 __attribute__((ext_vector_type(4)));
typedef float f32x16 __attribute__((ext_vector_type(16)));
typedef unsigned short u16;

#define MFMA16(a, b, c) __builtin_amdgcn_mfma_f32_16x16x32_bf16(a, b, c, 0, 0, 0)
#define MFMA32(a, b, c) __builtin_amdgcn_mfma_f32_32x32x16_bf16(a, b, c, 0, 0, 0)
#define GLOAD_LDS16(gp, lp)                                        \
  __builtin_amdgcn_global_load_lds(                                \
      (const __attribute__((address_space(1))) unsigned int*)(gp), \
      (__attribute__((address_space(3))) unsigned int*)(lp), 16, 0, 0)

__device__ __forceinline__ u16 bf16r(float x) {
  union { float f; unsigned int u; } c; c.f = x;
  unsigned int u = c.u + 0x7fffu + ((c.u >> 16) & 1u);
  return (u16)(u >> 16);
}

__device__ __forceinline__ unsigned int cvt_pk_bf16(float lo, float hi) {
  unsigned int r;
  asm("v_cvt_pk_bf16_f32 %0, %1, %2" : "=v"(r) : "v"(lo), "v"(hi));
  return r;
}

__device__ __forceinline__ float fexp2(float x) {
  float r;
  asm("v_exp_f32 %0, %1" : "=v"(r) : "v"(x));
  return r;
}

// V k-axis permutation so the PV A-fragment (32x32x16 layout: k=(lane>>5)*8+e)
// is exactly the lane's own QK^T output regs (k=(reg&3)+8*(reg>>2)+4*(lane>>5)).
// Required map is the involution "swap bits 2 and 3" of the k index.
__device__ __forceinline__ int sigma64(int s) {
  return (s & ~12) | ((s & 4) << 1) | ((s & 8) >> 1);
}

// ---- fused preprocessing: V-transpose(+k-perm) | K cvt | W cvt | mask flags ----
__global__ __launch_bounds__(256) void prep_kernel(
    const float* __restrict__ values, const float* __restrict__ keys,
    const float* __restrict__ W, const int* __restrict__ mask,
    u16* __restrict__ vt, u16* __restrict__ kb, u16* __restrict__ wb,
    unsigned char* __restrict__ fl2) {
  __shared__ u16 tile[64][65];
  __shared__ int s_ok[4];
  int b = blockIdx.x;
  int t = threadIdx.x;
  if (b < 1024) {
    // V transpose: v[n][s][h*64+d] fp32 -> vt[n][h][d][sigma(s)] bf16
    int st = b & 31, h = (b >> 5) & 15, n = b >> 9;
    int s0 = st * 64;
    int d = t & 63, r4 = t >> 6;
#pragma unroll
    for (int i = 0; i < 16; ++i) {
      int s = r4 + i * 4;
      float x = values[(size_t)(n * S_LEN + s0 + s) * EMB + h * HD + d];
      tile[s][d] = bf16r(x);
    }
    __syncthreads();
    int sp = s0 + sigma64(d);  // permuted column position
#pragma unroll
    for (int i = 0; i < 16; ++i) {
      int dd = r4 + i * 4;
      vt[(size_t)((n * NHEADS + h) * HD + dd) * S_LEN + sp] = tile[d][dd];
    }
  } else if (b < 2048) {
    // K fp32 -> bf16 (1,048,576 float4)
    int idx = (b - 1024) * 256 + t;
    const float4* in4 = (const float4*)keys;
    ushort4* out4 = (ushort4*)kb;
#pragma unroll
    for (int j = 0; j < 4; ++j) {
      float4 v = in4[idx + j * 262144];
      ushort4 o;
      o.x = bf16r(v.x); o.y = bf16r(v.y); o.z = bf16r(v.z); o.w = bf16r(v.w);
      out4[idx + j * 262144] = o;
    }
  } else if (b < 2304) {
    // W fp32 -> bf16 (262,144 float4)
    int idx = (b - 2048) * 256 + t;
    const float4* in4 = (const float4*)W;
    ushort4* out4 = (ushort4*)wb;
#pragma unroll
    for (int j = 0; j < 4; ++j) {
      float4 v = in4[idx + j * 65536];
      ushort4 o;
      o.x = bf16r(v.x); o.y = bf16r(v.y); o.z = bf16r(v.z); o.w = bf16r(v.w);
      out4[idx + j * 65536] = o;
    }
  } else {
    // mask flags: fl2[(n*16+qt)*32+kt] = all(mask block 128q x 64k != 0)
    int idx = b - 2304;
    int kt = idx & 31, qt = (idx >> 5) & 15, n = idx >> 9;
    int qr = t >> 1, c8 = t & 1;
    const int4* mp = (const int4*)(mask + (size_t)n * S_LEN * S_LEN +
                                   (size_t)(qt * 128 + qr) * S_LEN + kt * 64) + c8 * 8;
    int ok = 1;
#pragma unroll
    for (int i = 0; i < 8; ++i) {
      int4 m = mp[i];
      ok &= (m.x != 0) & (m.y != 0) & (m.z != 0) & (m.w != 0);
    }
    ok = __all(ok);
    if ((t & 63) == 0) s_ok[t >> 6] = ok;
    __syncthreads();
    if (t == 0) fl2[idx] = (unsigned char)(s_ok[0] & s_ok[1] & s_ok[2] & s_ok[3]);
  }
}

// ---- flash attention: 2 waves x 32 q = 64 q/block, KVBLK=64, 32x32x16 MFMA ----
// Swapped QK^T (lane owns ONE q-row across 32 k-regs), defer-max, in-register P
// (bit-2/3-swapped V), log2-domain softmax, prefetch dbuf staging, 4 blocks/CU.
__global__ __launch_bounds__(128, 2) void attn_kernel(
    const float* __restrict__ query, const u16* __restrict__ kbuf,
    const u16* __restrict__ vt, const int* __restrict__ mask,
    const unsigned char* __restrict__ fl2, u16* __restrict__ ob) {
  __shared__ __align__(16) unsigned char kl[2][8192];  // K tile [64 k][64 d] dbuf, swizzled
  __shared__ __align__(16) unsigned char vl[2][8192];  // Vt tile [64 d][64 k'] dbuf, swizzled

  int b = blockIdx.x;
  b = (b & 7) * 128 + (b >> 3);  // XCD swizzle: 4 (n,h) pairs per XCD -> K/V L2-resident
  int qt = b & 31, h = (b >> 5) & 15, n = b >> 9;
  int t = threadIdx.x, w = t >> 6, l = t & 63;
  int l31 = l & 31, lh = l >> 5;
  int q0 = qt * 64 + w * 32;  // wave q base; this lane's q = q0 + l31

  // Q fragments (B-operand): col=q=l31, k-elem d = dj*16 + lh*8 + e.
  // Pre-scale by LOG2E/32 -> QK output directly in log2 domain.
  const float QS = 0.03125f * LOG2E;
  bf16x8 qf[4];
  const float* qp = query + (size_t)(n * S_LEN + q0 + l31) * EMB + h * HD + lh * 8;
#pragma unroll
  for (int dj = 0; dj < 4; ++dj) {
    float4 f0 = *(const float4*)(qp + dj * 16);
    float4 f1 = *(const float4*)(qp + dj * 16 + 4);
    union { bf16x8 v; unsigned int u32[4]; } qq;
    qq.u32[0] = cvt_pk_bf16(f0.x * QS, f0.y * QS);
    qq.u32[1] = cvt_pk_bf16(f0.z * QS, f0.w * QS);
    qq.u32[2] = cvt_pk_bf16(f1.x * QS, f1.y * QS);
    qq.u32[3] = cvt_pk_bf16(f1.z * QS, f1.w * QS);
    qf[dj] = qq.v;
  }

  f32x16 zero16 = {0.f, 0.f, 0.f, 0.f, 0.f, 0.f, 0.f, 0.f,
                   0.f, 0.f, 0.f, 0.f, 0.f, 0.f, 0.f, 0.f};
  f32x16 acc0 = zero16, acc1 = zero16;
  float lrun = 0.f, mrun = 0.f;

  int row_s = t >> 3, cc = t & 7;  // staging row 0..15, 16B chunk 0..7
  int sc = cc ^ (row_s & 7);       // pre-swizzled source chunk
  const u16* gk0 = kbuf + (size_t)(n * S_LEN + row_s) * EMB + h * HD + sc * 8;
  const u16* gv0 = vt + (size_t)((n * NHEADS + h) * HD + row_s) * S_LEN + sc * 8;

  auto stage = [&](int kt, int nb) {
    const u16* gk = gk0 + (size_t)kt * 64 * EMB;
    const u16* gv = gv0 + kt * 64;
#pragma unroll
    for (int i = 0; i < 4; ++i) {
      GLOAD_LDS16(gk + (size_t)i * 16 * EMB, kl[nb] + i * 2048 + w * 1024);
      GLOAD_LDS16(gv + i * 16 * S_LEN, vl[nb] + i * 2048 + w * 1024);
    }
  };

  stage(0, 0);
  __syncthreads();  // tile 0 staged

  for (int kt = 0; kt < S_LEN / 64; ++kt) {
    int cur = kt & 1;
    if (kt + 1 < S_LEN / 64) stage(kt + 1, cur ^ 1);  // prefetch next tile
    const unsigned char* kc = kl[cur];
    const unsigned char* vc = vl[cur];

    // S^T = K Q^T : col=q=l31; s0 regs hold k = (r&3)+8*(r>>2)+4*lh, s1 +32
    f32x16 s0 = zero16, s1 = zero16;
    __builtin_amdgcn_s_setprio(1);
    {
      int row = l31;
      const unsigned char* kr = kc + row * 128;
      int sw = (row & 7) << 4;
#pragma unroll
      for (int dj = 0; dj < 4; ++dj) {
        bf16x8 ka = *(const bf16x8*)(kr + ((dj * 32 + lh * 16) ^ sw));
        s0 = MFMA32(ka, qf[dj], s0);
      }
      const unsigned char* kr1 = kc + (32 + row) * 128;
#pragma unroll
      for (int dj = 0; dj < 4; ++dj) {
        bf16x8 ka = *(const bf16x8*)(kr1 + ((dj * 32 + lh * 16) ^ sw));
        s1 = MFMA32(ka, qf[dj], s1);
      }
    }
    __builtin_amdgcn_s_setprio(0);

    unsigned char ff = fl2[((n * 16 + (qt >> 1)) * 32) + kt];
    if (!ff) {  // rare: per-element mask (log2 domain: -100 ~ zero prob)
      const int* mrow = mask + (size_t)n * S_LEN * S_LEN +
                        (size_t)(q0 + l31) * S_LEN + kt * 64 + lh * 4;
#pragma unroll
      for (int bq = 0; bq < 4; ++bq) {
        int4 m0 = *(const int4*)(mrow + bq * 8);
        int4 m1 = *(const int4*)(mrow + 32 + bq * 8);
        if (m0.x == 0) s0[4 * bq + 0] = -100.f;
        if (m0.y == 0) s0[4 * bq + 1] = -100.f;
        if (m0.z == 0) s0[4 * bq + 2] = -100.f;
        if (m0.w == 0) s0[4 * bq + 3] = -100.f;
        if (m1.x == 0) s1[4 * bq + 0] = -100.f;
        if (m1.y == 0) s1[4 * bq + 1] = -100.f;
        if (m1.z == 0) s1[4 * bq + 2] = -100.f;
        if (m1.w == 0) s1[4 * bq + 3] = -100.f;
      }
    }

    // defer-max over this lane's 32 values (half of one q-row; other half in lane^32)
    float mx0 = fmaxf(s0[0], s0[1]), mx1 = fmaxf(s0[2], s0[3]);
    float mx2 = fmaxf(s0[4], s0[5]), mx3 = fmaxf(s0[6], s0[7]);
#pragma unroll
    for (int i = 8; i < 16; i += 4) {
      mx0 = fmaxf(mx0, fmaxf(s0[i], s0[i + 1]));
      mx1 = fmaxf(mx1, fmaxf(s0[i + 2], s0[i + 3]));
    }
#pragma unroll
    for (int i = 0; i < 16; i += 4) {
      mx2 = fmaxf(mx2, fmaxf(s1[i], s1[i + 1]));
      mx3 = fmaxf(mx3, fmaxf(s1[i + 2], s1[i + 3]));
    }
    float lmax = fmaxf(fmaxf(mx0, mx1), fmaxf(mx2, mx3));
    if (!__all(lmax <= mrun + 8.f)) {  // rare rescale path
      float rmax = fmaxf(lmax, __shfl_xor(lmax, 32));
      float Mn = fmaxf(mrun, rmax);
      float corr = fexp2(mrun - Mn);
      mrun = Mn;
      lrun *= corr;
#pragma unroll
      for (int r = 0; r < 16; ++r) {
        float ca = __shfl(corr, (r & 3) + 8 * (r >> 2) + 4 * lh);
        acc0[r] *= ca;
        acc1[r] *= ca;
      }
    }

    // p = 2^(s - m), lane-partial sum (tree), pack A-frags from own regs
    float p0[16], p1[16];
#pragma unroll
    for (int i = 0; i < 16; ++i) p0[i] = fexp2(s0[i] - mrun);
#pragma unroll
    for (int i = 0; i < 16; ++i) p1[i] = fexp2(s1[i] - mrun);
    float q4[8];
#pragma unroll
    for (int i = 0; i < 4; ++i)
      q4[i] = (p0[4 * i] + p0[4 * i + 1]) + (p0[4 * i + 2] + p0[4 * i + 3]);
#pragma unroll
    for (int i = 0; i < 4; ++i)
      q4[4 + i] = (p1[4 * i] + p1[4 * i + 1]) + (p1[4 * i + 2] + p1[4 * i + 3]);
    lrun += ((q4[0] + q4[1]) + (q4[2] + q4[3])) + ((q4[4] + q4[5]) + (q4[6] + q4[7]));

    bf16x8 pa[4];
#pragma unroll
    for (int j = 0; j < 4; ++j) {
      const float* ps = (j < 2) ? p0 : p1;
      int o = (j & 1) * 8;
      union { bf16x8 v; unsigned int u32[4]; } pp;
      pp.u32[0] = cvt_pk_bf16(ps[o + 0], ps[o + 1]);
      pp.u32[1] = cvt_pk_bf16(ps[o + 2], ps[o + 3]);
      pp.u32[2] = cvt_pk_bf16(ps[o + 4], ps[o + 5]);
      pp.u32[3] = cvt_pk_bf16(ps[o + 6], ps[o + 7]);
      pa[j] = pp.v;
    }

    // O += P V : A = in-register P, B = permuted Vt rows
    __builtin_amdgcn_s_setprio(1);
    {
      const unsigned char* vr = vc + l31 * 128;
      int sw = (l31 & 7) << 4;
#pragma unroll
      for (int j = 0; j < 4; ++j) {
        bf16x8 bv = *(const bf16x8*)(vr + ((j * 32 + lh * 16) ^ sw));
        acc0 = MFMA32(pa[j], bv, acc0);
      }
      const unsigned char* vr1 = vc + (32 + l31) * 128;
#pragma unroll
      for (int j = 0; j < 4; ++j) {
        bf16x8 bv = *(const bf16x8*)(vr1 + ((j * 32 + lh * 16) ^ sw));
        acc1 = MFMA32(pa[j], bv, acc1);
      }
    }
    __builtin_amdgcn_s_setprio(0);

    __syncthreads();  // both waves done with cur; prefetch landed
  }

  // epilogue: total row sum (lane pair), normalize, store
  float ltot = lrun + __shfl_xor(lrun, 32);
  float own_rinv = 1.f / ltot;
#pragma unroll
  for (int r = 0; r < 16; ++r) {
    int qr = (r & 3) + 8 * (r >> 2) + 4 * lh;
    float rinv = __shfl(own_rinv, qr);
    size_t base = (size_t)(n * S_LEN + q0 + qr) * EMB + h * HD;
    ob[base + l31] = bf16r(acc0[r] * rinv);
    ob[base + 32 + l31] = bf16r(acc1[r] * rinv);
  }
}

// ---- output projection: C[4096][1024] = O_bf16 @ W_bf16^T + bias ----
// 128x64 tile, grid (32,16) = 512 blocks (2/CU), prefetch dbuf staging.
__global__ __launch_bounds__(256) void proj_kernel(
    const u16* __restrict__ A, const u16* __restrict__ Bt,
    const float* __restrict__ bias, float* __restrict__ C) {
  __shared__ __align__(16) unsigned char al[2][16384];
  __shared__ __align__(16) unsigned char bl[2][8192];
  int bm = blockIdx.x, bn = blockIdx.y;
  int t = threadIdx.x, w = t >> 6, l = t & 63;
  int l16 = l & 15, g = l >> 4;
  f32x4 zero4 = {0.f, 0.f, 0.f, 0.f};
  f32x4 acc[2][4];
#pragma unroll
  for (int mi = 0; mi < 2; ++mi)
#pragma unroll
    for (int nj = 0; nj < 4; ++nj) acc[mi][nj] = zero4;
  int row_s = t >> 3, cc = t & 7;
  int sc = cc ^ (row_s & 7);
  const u16* ga0 = A + (size_t)(bm * 128 + row_s) * EMB + sc * 8;
  const u16* gb0 = Bt + (size_t)(bn * 64 + row_s) * EMB + sc * 8;

  auto stage = [&](int ks, int nb) {
#pragma unroll
    for (int i = 0; i < 4; ++i)
      GLOAD_LDS16(ga0 + (size_t)i * 32 * EMB + ks * 64, al[nb] + (i * 256 + w * 64) * 16);
#pragma unroll
    for (int i = 0; i < 2; ++i)
      GLOAD_LDS16(gb0 + (size_t)i * 32 * EMB + ks * 64, bl[nb] + (i * 256 + w * 64) * 16);
  };

  stage(0, 0);
  __syncthreads();

  for (int ks = 0; ks < 16; ++ks) {
    int cur = ks & 1;
    if (ks + 1 < 16) stage(ks + 1, cur ^ 1);
    __builtin_amdgcn_s_setprio(1);
#pragma unroll
    for (int hh = 0; hh < 2; ++hh) {
      bf16x8 af[2], bfr[4];
#pragma unroll
      for (int mi = 0; mi < 2; ++mi) {
        int row = w * 32 + mi * 16 + l16;
        af[mi] = *(const bf16x8*)(al[cur] + row * 128 + ((hh * 64 + g * 16) ^ ((row & 7) << 4)));
      }
#pragma unroll
      for (int nj = 0; nj < 4; ++nj) {
        int row = nj * 16 + l16;
        bfr[nj] = *(const bf16x8*)(bl[cur] + row * 128 + ((hh * 64 + g * 16) ^ ((row & 7) << 4)));
      }
#pragma unroll
      for (int mi = 0; mi < 2; ++mi)
#pragma unroll
        for (int nj = 0; nj < 4; ++nj) acc[mi][nj] = MFMA16(af[mi], bfr[nj], acc[mi][nj]);
    }
    __builtin_amdgcn_s_setprio(0);
    __syncthreads();
  }
#pragma unroll
  for (int nj = 0; nj < 4; ++nj) {
    int j = bn * 64 + nj * 16 + l16;
    float bj = bias[j];
#pragma unroll
    for (int mi = 0; mi < 2; ++mi) {
      int i0 = bm * 128 + w * 32 + mi * 16 + g * 4;
#pragma unroll
      for (int r = 0; r < 4; ++r) C[(size_t)(i0 + r) * EMB + j] = acc[mi][nj][r] + bj;
    }
  }
}

extern "C" void kernel_launch(void* const* d_in, const int* in_sizes, int n_in,
                              void* d_out, int out_size, void* d_ws, size_t ws_size,
                              hipStream_t stream) {
  const float* values = (const float*)d_in[0];
  const float* keys = (const float*)d_in[1];
  const float* query = (const float*)d_in[2];
  const int* mask = (const int*)d_in[3];
  const float* W = (const float*)d_in[4];
  const float* bias = (const float*)d_in[5];
  float* out = (float*)d_out;

  u16* kb = (u16*)d_ws;
  u16* vt = kb + 4194304;
  u16* ob = vt + 4194304;
  u16* wb = ob + 4194304;
  unsigned char* fl2 = (unsigned char*)(wb + 1048576);

  prep_kernel<<<3328, 256, 0, stream>>>(values, keys, W, mask, vt, kb, wb, fl2);
  attn_kernel<<<1024, 128, 0, stream>>>(query, kb, vt, mask, fl2, ob);
  proj_kernel<<<dim3(32, 16), 256, 0, stream>>>(ob, wb, bias, out);
}

// Round 7
// 90.231 us; speedup vs baseline: 1.1655x; 1.1655x over previous
//
#include <hip/hip_runtime.h>
#include <stdint.h>

// Problem constants (N=2, S=2048, E=1024, H=16, D=64)
#define S_LEN 2048
#define EMB 1024
#define NHEADS 16
#define HD 64
#define LOG2E 1.4426950408889634f

typedef __bf16 bf16x8 __attribute__((ext_vector_type(8)));
typedef float f32x4 __attribute__((ext_vector_type(4)));
typedef unsigned short u16;

#define MFMA16(a, b, c) __builtin_amdgcn_mfma_f32_16x16x32_bf16(a, b, c, 0, 0, 0)
#define GLOAD_LDS16(gp, lp)                                        \
  __builtin_amdgcn_global_load_lds(                                \
      (const __attribute__((address_space(1))) unsigned int*)(gp), \
      (__attribute__((address_space(3))) unsigned int*)(lp), 16, 0, 0)

__device__ __forceinline__ u16 bf16r(float x) {
  union { float f; unsigned int u; } c; c.f = x;
  unsigned int u = c.u + 0x7fffu + ((c.u >> 16) & 1u);
  return (u16)(u >> 16);
}

__device__ __forceinline__ unsigned int cvt_pk_bf16(float lo, float hi) {
  unsigned int r;
  asm("v_cvt_pk_bf16_f32 %0, %1, %2" : "=v"(r) : "v"(lo), "v"(hi));
  return r;
}

__device__ __forceinline__ float fexp2(float x) {
  float r;
  asm("v_exp_f32 %0, %1" : "=v"(r) : "v"(x));
  return r;
}

// k-axis permutation applied to V columns so the PV A-fragment (P) is formed
// from each lane's own QK^T outputs with zero cross-lane traffic (16x16 MFMA).
// QK^T(swapped) lane (l16,g) holds P[q=l16][k=kb*16+g*4+r]; A-frag slot
// (hh,g,e) takes kb=2hh+(e>>2), r=e&3.
__device__ __forceinline__ int kperm(int k) {
  int kb = (k >> 4) & 3, g = (k >> 2) & 3, r = k & 3;
  return (kb >> 1) * 32 + g * 8 + (kb & 1) * 4 + r;
}

// ---- fused preprocessing: V-transpose(+k-perm) | K cvt | W cvt | mask flags ----
__global__ __launch_bounds__(256) void prep_kernel(
    const float* __restrict__ values, const float* __restrict__ keys,
    const float* __restrict__ W, const int* __restrict__ mask,
    u16* __restrict__ vt, u16* __restrict__ kb, u16* __restrict__ wb,
    unsigned char* __restrict__ fl2) {
  __shared__ u16 tile[64][65];
  __shared__ int s_ok[4];
  int b = blockIdx.x;
  int t = threadIdx.x;
  if (b < 1024) {
    // V transpose: v[n][s][h*64+d] fp32 -> vt[n][h][d][kperm(s)] bf16
    int st = b & 31, h = (b >> 5) & 15, n = b >> 9;
    int s0 = st * 64;
    int d = t & 63, r4 = t >> 6;
#pragma unroll
    for (int i = 0; i < 16; ++i) {
      int s = r4 + i * 4;
      float x = values[(size_t)(n * S_LEN + s0 + s) * EMB + h * HD + d];
      tile[s][d] = bf16r(x);
    }
    __syncthreads();
    int sp = s0 + kperm(d);  // permuted column position
#pragma unroll
    for (int i = 0; i < 16; ++i) {
      int dd = r4 + i * 4;
      vt[(size_t)((n * NHEADS + h) * HD + dd) * S_LEN + sp] = tile[d][dd];
    }
  } else if (b < 2048) {
    // K fp32 -> bf16 (1,048,576 float4)
    int idx = (b - 1024) * 256 + t;
    const float4* in4 = (const float4*)keys;
    ushort4* out4 = (ushort4*)kb;
#pragma unroll
    for (int j = 0; j < 4; ++j) {
      float4 v = in4[idx + j * 262144];
      ushort4 o;
      o.x = bf16r(v.x); o.y = bf16r(v.y); o.z = bf16r(v.z); o.w = bf16r(v.w);
      out4[idx + j * 262144] = o;
    }
  } else if (b < 2304) {
    // W fp32 -> bf16 (262,144 float4)
    int idx = (b - 2048) * 256 + t;
    const float4* in4 = (const float4*)W;
    ushort4* out4 = (ushort4*)wb;
#pragma unroll
    for (int j = 0; j < 4; ++j) {
      float4 v = in4[idx + j * 65536];
      ushort4 o;
      o.x = bf16r(v.x); o.y = bf16r(v.y); o.z = bf16r(v.z); o.w = bf16r(v.w);
      out4[idx + j * 65536] = o;
    }
  } else {
    // mask flags: fl2[(n*16+qt)*32+kt] = all(mask block 128q x 64k != 0)
    int idx = b - 2304;
    int kt = idx & 31, qt = (idx >> 5) & 15, n = idx >> 9;
    int qr = t >> 1, c8 = t & 1;
    const int4* mp = (const int4*)(mask + (size_t)n * S_LEN * S_LEN +
                                   (size_t)(qt * 128 + qr) * S_LEN + kt * 64) + c8 * 8;
    int ok = 1;
#pragma unroll
    for (int i = 0; i < 8; ++i) {
      int4 m = mp[i];
      ok &= (m.x != 0) & (m.y != 0) & (m.z != 0) & (m.w != 0);
    }
    ok = __all(ok);
    if ((t & 63) == 0) s_ok[t >> 6] = ok;
    __syncthreads();
    if (t == 0) fl2[idx] = (unsigned char)(s_ok[0] & s_ok[1] & s_ok[2] & s_ok[3]);
  }
}

// ---- flash attention: 4 waves x 32 q (2x16 subtiles) = 128 q/block, KVBLK=64 ----
// Swapped QK^T, log2-domain softmax (Q pre-scaled by LOG2E/32), defer-max,
// in-register P (k-permuted V), K/V fragments shared across both subtiles,
// prefetch dbuf staging. 16x16 MFMA (conflict-free read pattern, measured 0).
__global__ __launch_bounds__(256, 2) void attn_kernel(
    const float* __restrict__ query, const u16* __restrict__ kbuf,
    const u16* __restrict__ vt, const int* __restrict__ mask,
    const unsigned char* __restrict__ fl2, u16* __restrict__ ob) {
  __shared__ __align__(16) unsigned char kl[2][8192];  // K tile [64 k][64 d] dbuf, swizzled
  __shared__ __align__(16) unsigned char vl[2][8192];  // Vt tile [64 d][64 k'] dbuf, swizzled

  int b = blockIdx.x;
  b = (b & 7) * 64 + (b >> 3);  // XCD swizzle: 4 (n,h) pairs per XCD -> K/V L2-resident
  int qt = b & 15, h = (b >> 4) & 15, n = b >> 8;
  int t = threadIdx.x, w = t >> 6, l = t & 63, l16 = l & 15, g = l >> 4;
  int q0 = qt * 128 + w * 32;  // wave q base; subtile u covers q0+u*16 .. +15

  // Q fragments (B-operand of swapped QK): pre-scale by LOG2E/32 -> log2 domain
  const float QS = 0.03125f * LOG2E;
  bf16x8 aq[2][2];
#pragma unroll
  for (int u = 0; u < 2; ++u)
#pragma unroll
    for (int hh = 0; hh < 2; ++hh) {
      const float* qp = query + (size_t)(n * S_LEN + q0 + u * 16 + l16) * EMB +
                        h * HD + hh * 32 + g * 8;
      float4 f0 = *(const float4*)qp;
      float4 f1 = *(const float4*)(qp + 4);
      union { bf16x8 v; unsigned int u32[4]; } qq;
      qq.u32[0] = cvt_pk_bf16(f0.x * QS, f0.y * QS);
      qq.u32[1] = cvt_pk_bf16(f0.z * QS, f0.w * QS);
      qq.u32[2] = cvt_pk_bf16(f1.x * QS, f1.y * QS);
      qq.u32[3] = cvt_pk_bf16(f1.z * QS, f1.w * QS);
      aq[u][hh] = qq.v;
    }

  f32x4 zero4 = {0.f, 0.f, 0.f, 0.f};
  f32x4 acc[2][4];
  float lrun[2] = {0.f, 0.f}, mrun[2] = {0.f, 0.f};
#pragma unroll
  for (int u = 0; u < 2; ++u)
#pragma unroll
    for (int db = 0; db < 4; ++db) acc[u][db] = zero4;

  int row_s = t >> 3, cc = t & 7;  // staging row 0..31, 16B chunk 0..7
  int sc = cc ^ (row_s & 7);       // pre-swizzled source chunk
  const u16* gk0 = kbuf + (size_t)(n * S_LEN + row_s) * EMB + h * HD + sc * 8;
  const u16* gv0 = vt + (size_t)((n * NHEADS + h) * HD + row_s) * S_LEN + sc * 8;

  auto stage = [&](int kt, int nb) {
    const u16* gk = gk0 + (size_t)kt * 64 * EMB;
    const u16* gv = gv0 + kt * 64;
    GLOAD_LDS16(gk, kl[nb] + (w * 64) * 16);
    GLOAD_LDS16(gk + 32 * EMB, kl[nb] + (256 + w * 64) * 16);
    GLOAD_LDS16(gv, vl[nb] + (w * 64) * 16);
    GLOAD_LDS16(gv + 32 * S_LEN, vl[nb] + (256 + w * 64) * 16);
  };

  stage(0, 0);
  __syncthreads();  // tile 0 staged

  for (int kt = 0; kt < S_LEN / 64; ++kt) {
    int cur = kt & 1;
    if (kt + 1 < S_LEN / 64) stage(kt + 1, cur ^ 1);  // prefetch next tile
    const unsigned char* kc = kl[cur];
    const unsigned char* vc = vl[cur];

    // S^T = K Q^T : lane (l16,g) -> S[k=kb*16+g*4+r][q=q0+u*16+l16] (log2 units)
    f32x4 sf[2][4];
    __builtin_amdgcn_s_setprio(1);
#pragma unroll
    for (int kb = 0; kb < 4; ++kb) {
      int row = kb * 16 + l16;
      const unsigned char* kr = kc + row * 128;
      int sw = (row & 7) << 4;
      bf16x8 bk0 = *(const bf16x8*)(kr + ((g * 16) ^ sw));
      bf16x8 bk1 = *(const bf16x8*)(kr + ((64 + g * 16) ^ sw));
#pragma unroll
      for (int u = 0; u < 2; ++u) {
        f32x4 z = zero4;
        z = MFMA16(bk0, aq[u][0], z);
        z = MFMA16(bk1, aq[u][1], z);
        sf[u][kb] = z;
      }
    }
    __builtin_amdgcn_s_setprio(0);

    unsigned char fflag = fl2[((n * 16 + qt) * 32) + kt];
    if (!fflag) {  // rare: per-element mask (log2 domain: -100 ~ zero prob)
#pragma unroll
      for (int u = 0; u < 2; ++u) {
        const int* mrow = mask + (size_t)n * S_LEN * S_LEN +
                          (size_t)(q0 + u * 16 + l16) * S_LEN + kt * 64 + g * 4;
#pragma unroll
        for (int kb = 0; kb < 4; ++kb) {
          int4 mm = *(const int4*)(mrow + kb * 16);
          if (mm.x == 0) sf[u][kb][0] = -100.f;
          if (mm.y == 0) sf[u][kb][1] = -100.f;
          if (mm.z == 0) sf[u][kb][2] = -100.f;
          if (mm.w == 0) sf[u][kb][3] = -100.f;
        }
      }
    }

    bf16x8 pa[2][2];
#pragma unroll
    for (int u = 0; u < 2; ++u) {
      // defer-max: in-register max over this lane's 16 values (one q-row)
      float lmax = sf[u][0][0];
#pragma unroll
      for (int kb = 0; kb < 4; ++kb)
#pragma unroll
        for (int r = 0; r < 4; ++r) lmax = fmaxf(lmax, sf[u][kb][r]);
      if (!__all(lmax <= mrun[u] + 8.f)) {  // rare rescale path
        float rmax = fmaxf(lmax, __shfl_xor(lmax, 16));
        rmax = fmaxf(rmax, __shfl_xor(rmax, 32));
        float Mn = fmaxf(mrun[u], rmax);
        float corr = fexp2(mrun[u] - Mn);
        mrun[u] = Mn;
        lrun[u] *= corr;
#pragma unroll
        for (int r = 0; r < 4; ++r) {
          float ca = __shfl(corr, (l & 48) + (g << 2) + r);
#pragma unroll
          for (int db = 0; db < 4; ++db) acc[u][db][r] *= ca;
        }
      }
      // p = 2^(s - m), lane-partial sum, pack A-fragments in-register (k-perm)
      float p[4][4];
#pragma unroll
      for (int kb = 0; kb < 4; ++kb)
#pragma unroll
        for (int r = 0; r < 4; ++r)
          p[kb][r] = fexp2(sf[u][kb][r] - mrun[u]);
      float s01 = (p[0][0] + p[0][1]) + (p[0][2] + p[0][3]);
      float s23 = (p[1][0] + p[1][1]) + (p[1][2] + p[1][3]);
      float s45 = (p[2][0] + p[2][1]) + (p[2][2] + p[2][3]);
      float s67 = (p[3][0] + p[3][1]) + (p[3][2] + p[3][3]);
      lrun[u] += (s01 + s23) + (s45 + s67);
#pragma unroll
      for (int hh = 0; hh < 2; ++hh) {
        union { bf16x8 v; unsigned int u32[4]; } pp;
        pp.u32[0] = cvt_pk_bf16(p[2 * hh][0], p[2 * hh][1]);
        pp.u32[1] = cvt_pk_bf16(p[2 * hh][2], p[2 * hh][3]);
        pp.u32[2] = cvt_pk_bf16(p[2 * hh + 1][0], p[2 * hh + 1][1]);
        pp.u32[3] = cvt_pk_bf16(p[2 * hh + 1][2], p[2 * hh + 1][3]);
        pa[u][hh] = pp.v;
      }
    }

    // O += P V : A = in-register P, B = permuted Vt rows shared across subtiles
    __builtin_amdgcn_s_setprio(1);
#pragma unroll
    for (int hh = 0; hh < 2; ++hh)
#pragma unroll
      for (int db = 0; db < 4; ++db) {
        int d = db * 16 + l16;
        bf16x8 bv = *(const bf16x8*)(vc + d * 128 + ((hh * 64 + g * 16) ^ ((d & 7) << 4)));
        acc[0][db] = MFMA16(pa[0][hh], bv, acc[0][db]);
        acc[1][db] = MFMA16(pa[1][hh], bv, acc[1][db]);
      }
    __builtin_amdgcn_s_setprio(0);

    __syncthreads();  // all waves done reading cur; prefetch landed
  }

  // epilogue: reduce lane-partial sums across g-groups, redistribute to acc rows
#pragma unroll
  for (int u = 0; u < 2; ++u) {
    float s = lrun[u];
    s += __shfl_xor(s, 16);
    s += __shfl_xor(s, 32);
    float rinv[4];
#pragma unroll
    for (int r = 0; r < 4; ++r) {
      float sr = __shfl(s, (l & 48) + (g << 2) + r);
      rinv[r] = 1.f / sr;
    }
#pragma unroll
    for (int db = 0; db < 4; ++db)
#pragma unroll
      for (int r = 0; r < 4; ++r) {
        int qg = q0 + u * 16 + (g << 2) + r;
        ob[(size_t)(n * S_LEN + qg) * EMB + h * HD + db * 16 + l16] =
            bf16r(acc[u][db][r] * rinv[r]);
      }
  }
}

// ---- output projection: C[4096][1024] = O_bf16 @ W_bf16^T + bias ----
// 128x64 tile, grid (32,16) = 512 blocks (2/CU), prefetch dbuf staging.
__global__ __launch_bounds__(256) void proj_kernel(
    const u16* __restrict__ A, const u16* __restrict__ Bt,
    const float* __restrict__ bias, float* __restrict__ C) {
  __shared__ __align__(16) unsigned char al[2][16384];
  __shared__ __align__(16) unsigned char bl[2][8192];
  int bm = blockIdx.x, bn = blockIdx.y;
  int t = threadIdx.x, w = t >> 6, l = t & 63;
  int l16 = l & 15, g = l >> 4;
  f32x4 zero4 = {0.f, 0.f, 0.f, 0.f};
  f32x4 acc[2][4];
#pragma unroll
  for (int mi = 0; mi < 2; ++mi)
#pragma unroll
    for (int nj = 0; nj < 4; ++nj) acc[mi][nj] = zero4;
  int row_s = t >> 3, cc = t & 7;
  int sc = cc ^ (row_s & 7);
  const u16* ga0 = A + (size_t)(bm * 128 + row_s) * EMB + sc * 8;
  const u16* gb0 = Bt + (size_t)(bn * 64 + row_s) * EMB + sc * 8;

  auto stage = [&](int ks, int nb) {
#pragma unroll
    for (int i = 0; i < 4; ++i)
      GLOAD_LDS16(ga0 + (size_t)i * 32 * EMB + ks * 64, al[nb] + (i * 256 + w * 64) * 16);
#pragma unroll
    for (int i = 0; i < 2; ++i)
      GLOAD_LDS16(gb0 + (size_t)i * 32 * EMB + ks * 64, bl[nb] + (i * 256 + w * 64) * 16);
  };

  stage(0, 0);
  __syncthreads();

  for (int ks = 0; ks < 16; ++ks) {
    int cur = ks & 1;
    if (ks + 1 < 16) stage(ks + 1, cur ^ 1);
    __builtin_amdgcn_s_setprio(1);
#pragma unroll
    for (int hh = 0; hh < 2; ++hh) {
      bf16x8 af[2], bfr[4];
#pragma unroll
      for (int mi = 0; mi < 2; ++mi) {
        int row = w * 32 + mi * 16 + l16;
        af[mi] = *(const bf16x8*)(al[cur] + row * 128 + ((hh * 64 + g * 16) ^ ((row & 7) << 4)));
      }
#pragma unroll
      for (int nj = 0; nj < 4; ++nj) {
        int row = nj * 16 + l16;
        bfr[nj] = *(const bf16x8*)(bl[cur] + row * 128 + ((hh * 64 + g * 16) ^ ((row & 7) << 4)));
      }
#pragma unroll
      for (int mi = 0; mi < 2; ++mi)
#pragma unroll
        for (int nj = 0; nj < 4; ++nj) acc[mi][nj] = MFMA16(af[mi], bfr[nj], acc[mi][nj]);
    }
    __builtin_amdgcn_s_setprio(0);
    __syncthreads();
  }
#pragma unroll
  for (int nj = 0; nj < 4; ++nj) {
    int j = bn * 64 + nj * 16 + l16;
    float bj = bias[j];
#pragma unroll
    for (int mi = 0; mi < 2; ++mi) {
      int i0 = bm * 128 + w * 32 + mi * 16 + g * 4;
#pragma unroll
      for (int r = 0; r < 4; ++r) C[(size_t)(i0 + r) * EMB + j] = acc[mi][nj][r] + bj;
    }
  }
}

extern "C" void kernel_launch(void* const* d_in, const int* in_sizes, int n_in,
                              void* d_out, int out_size, void* d_ws, size_t ws_size,
                              hipStream_t stream) {
  const float* values = (const float*)d_in[0];
  const float* keys = (const float*)d_in[1];
  const float* query = (const float*)d_in[2];
  const int* mask = (const int*)d_in[3];
  const float* W = (const float*)d_in[4];
  const float* bias = (const float*)d_in[5];
  float* out = (float*)d_out;

  u16* kb = (u16*)d_ws;
  u16* vt = kb + 4194304;
  u16* ob = vt + 4194304;
  u16* wb = ob + 4194304;
  unsigned char* fl2 = (unsigned char*)(wb + 1048576);

  prep_kernel<<<3328, 256, 0, stream>>>(values, keys, W, mask, vt, kb, wb, fl2);
  attn_kernel<<<512, 256, 0, stream>>>(query, kb, vt, mask, fl2, ob);
  proj_kernel<<<dim3(32, 16), 256, 0, stream>>>(ob, wb, bias, out);
}